// Round 2
// baseline (179.072 us; speedup 1.0000x reference)
//
#include <hip/hip_runtime.h>
#include <hip/hip_bf16.h>

#define SLOPE 0.1f

// ---- ws int-index layout: [0]=bf flag ----
// ---- ws float-index layout ----
#define OFF_QW    1816    // 30   q_weights (softmax)
#define OFF_QNI   1846    // 30   1/||question_embeds[q]||
#define OFF_QNS   1876    // 30   1/||q_conv[q]||
#define OFF_QNN   1906    // 30   ||question_embeds[q]|| (raw norm, for one-hot thr)
#define OFF_B1    4606    // 30
#define OFF_B2    7336    // 30
#define OFF_LQ1W  7366    // 48
#define OFF_LQ1B  7414    // 8
#define OFF_LQ2W  7422    // 8
#define OFF_LQ2B  7430    // 1
#define OFF_SOW   7431    // 4
#define OFF_SOB   7435    // 1
#define OFF_FLW   7436    // 5
#define OFF_FLB   7441    // 1
// ---- bf16 (u16-index) region, starts at byte 32768 ----
#define U16_QEA   16384   // 32 rows x 32  (B-operand QE, zeros at d>=30, q>=30)
#define U16_QCA   17408   // 32 rows x 32  (B-operand QC)
#define U16_WB1   18432   // 32 rows x 96  (W1[o][kk'], kk'=k*32+i, zeros i>=30)
#define U16_WB2   21504   // 32 rows x 96

typedef __attribute__((ext_vector_type(8))) __bf16 bf16x8;
typedef __attribute__((ext_vector_type(4))) float f32x4;

union Frag { uint4 u4; uint u[4]; bf16x8 v; };

__device__ __forceinline__ float bf2f(ushort h) {
    union { uint u; float f; } c; c.u = ((uint)h) << 16; return c.f;
}
__device__ __forceinline__ ushort f2bf(float f) {   // RNE, finite inputs
    union { float f; uint u; } c; c.f = f;
    uint u = c.u;
    return (ushort)((u + 0x7FFFu + ((u >> 16) & 1u)) >> 16);
}
__device__ __forceinline__ float ldx(const void* p, long i, int bf) {
    if (bf) return bf2f(((const ushort*)p)[i]);
    return ((const float*)p)[i];
}
// pack two f32 -> one dword of 2x bf16 (RNE), single instruction on gfx950
__device__ __forceinline__ uint pk2(float lo, float hi) {
    uint r;
    asm("v_cvt_pk_bf16_f32 %0, %1, %2" : "=v"(r) : "v"(lo), "v"(hi));
    return r;
}
__device__ __forceinline__ float blo(uint u) { return __uint_as_float(u << 16); }
__device__ __forceinline__ float bhi(uint u) { return __uint_as_float(u & 0xFFFF0000u); }
__device__ __forceinline__ float lk(float x) { return fmaxf(x, SLOPE * x); }  // leaky, SLOPE<1

#define LGKM0() asm volatile("s_waitcnt lgkmcnt(0)" ::: "memory")

#define CE(x, y) { float _hi = fmaxf(x, y), _lo = fminf(x, y); x = _hi; y = _lo; }

__device__ __forceinline__ void sort4d(float& a, float& b, float& c, float& d) {
    CE(a, b); CE(c, d); CE(a, c); CE(b, d); CE(b, c);
}
// merge two sorted-desc 4-lists -> top5 desc
__device__ __forceinline__ void merge44_5(const float* a, const float* b, float* t) {
    t[0] = fmaxf(a[0], b[0]);
    t[1] = fmaxf(fminf(a[0], b[0]), fmaxf(a[1], b[1]));
    t[2] = fmaxf(fmaxf(fminf(a[0], b[1]), fminf(a[1], b[0])), fmaxf(a[2], b[2]));
    t[3] = fmaxf(fmaxf(fminf(a[0], b[2]), fminf(a[1], b[1])),
                 fmaxf(fminf(a[2], b[0]), fmaxf(a[3], b[3])));
    t[4] = fmaxf(fmaxf(fminf(a[0], b[3]), fminf(a[1], b[2])),
                 fmaxf(fminf(a[2], b[1]), fminf(a[3], b[0])));
}
// merge sorted5 + sorted4 -> top5
__device__ __forceinline__ void merge54_5(const float* a, const float* b, float* t) {
    t[0] = fmaxf(a[0], b[0]);
    t[1] = fmaxf(fminf(a[0], b[0]), fmaxf(a[1], b[1]));
    t[2] = fmaxf(fmaxf(fminf(a[0], b[1]), fminf(a[1], b[0])), fmaxf(a[2], b[2]));
    t[3] = fmaxf(fmaxf(fminf(a[0], b[2]), fminf(a[1], b[1])),
                 fmaxf(fminf(a[2], b[0]), fmaxf(a[3], b[3])));
    t[4] = fmaxf(fmaxf(fmaxf(fminf(a[0], b[3]), fminf(a[1], b[2])),
                       fmaxf(fminf(a[2], b[1]), fminf(a[3], b[0]))), a[4]);
}
// merge two sorted5 -> top5
__device__ __forceinline__ void merge55_5(const float* a, const float* b, float* t) {
    t[0] = fmaxf(a[0], b[0]);
    t[1] = fmaxf(fminf(a[0], b[0]), fmaxf(a[1], b[1]));
    t[2] = fmaxf(fmaxf(fminf(a[0], b[1]), fminf(a[1], b[0])), fmaxf(a[2], b[2]));
    t[3] = fmaxf(fmaxf(fminf(a[0], b[2]), fminf(a[1], b[1])),
                 fmaxf(fminf(a[2], b[0]), fmaxf(a[3], b[3])));
    t[4] = fmaxf(fmaxf(fmaxf(fminf(a[0], b[3]), fminf(a[1], b[2])),
                       fmaxf(fminf(a[2], b[1]), fminf(a[3], b[0]))),
                 fmaxf(a[4], b[4]));
}

// dtype detection: f32 mantissa words carry wild bf16-exponent fields
__device__ __forceinline__ int detect_bf(const void* doc_in, int tid, int* scnt) {
    if (tid == 0) *scnt = 0;
    __syncthreads();
    const ushort* p = (const ushort*)doc_in;
    int local = 0;
    for (int i = tid; i < 4096; i += 256) {
        unsigned e = (p[i] >> 7) & 0xFFu;
        if (e != 0u && (e < 100u || e > 134u)) local++;
    }
    atomicAdd(scnt, local);
    __syncthreads();
    return (*scnt > 200) ? 0 : 1;
}

// ---------------- kernel 1 (3 blocks): detect + question path + repack ----------------
__global__ __launch_bounds__(256) void k_prep(
        const void* doc_in,
        const void* qe_in, const void* qidf_in,
        const void* w1_in, const void* b1_in,
        const void* w2_in, const void* b2_in,
        const void* qwW_in, const void* qwb_in,
        const void* lq1W_in, const void* lq1b_in,
        const void* lq2W_in, const void* lq2b_in,
        const void* soW_in, const void* sob_in,
        const void* flW_in, const void* flb_in,
        float* ws) {
    const int tid = threadIdx.x;
    const int blk = blockIdx.x;
    __shared__ float QE[900], T1[900], QC[900], W[2700], IDF[32], LG[32];
    __shared__ int scnt;

    const int bf = detect_bf(doc_in, tid, &scnt);
    ushort* wsu = (ushort*)ws;

    if (blk == 1) {
        if (tid == 0) { ((int*)ws)[0] = bf; }
        if (tid < 30) ws[OFF_B1 + tid] = ldx(b1_in, tid, bf);
        if (tid < 48) ws[OFF_LQ1W + tid] = ldx(lq1W_in, tid, bf);
        if (tid < 8)  { ws[OFF_LQ1B + tid] = ldx(lq1b_in, tid, bf);
                        ws[OFF_LQ2W + tid] = ldx(lq2W_in, tid, bf); }
        if (tid < 4)  ws[OFF_SOW + tid] = ldx(soW_in, tid, bf);
        if (tid < 5)  ws[OFF_FLW + tid] = ldx(flW_in, tid, bf);
        if (tid == 1) { ws[OFF_LQ2B] = ldx(lq2b_in, 0, bf);
                        ws[OFF_SOB]  = ldx(sob_in, 0, bf);
                        ws[OFF_FLB]  = ldx(flb_in, 0, bf); }
        for (int i = tid; i < 3072; i += 256) {
            int o = i / 96, kk = i % 96;
            int k = kk >> 5, ii = kk & 31;      // kk' = k*32 + i, zeros at i>=30
            float v1 = 0.f;
            if (o < 30 && ii < 30) v1 = ldx(w1_in, (long)o*90 + ii*3 + k, bf);
            wsu[U16_WB1 + i] = f2bf(v1);
        }
        return;
    }
    if (blk == 2) {
        if (tid < 30) ws[OFF_B2 + tid] = ldx(b2_in, tid, bf);
        for (int i = tid; i < 3072; i += 256) {
            int o = i / 96, kk = i % 96;
            int k = kk >> 5, ii = kk & 31;
            float v2 = 0.f;
            if (o < 30 && ii < 30) v2 = ldx(w2_in, (long)o*90 + ii*3 + k, bf);
            wsu[U16_WB2 + i] = f2bf(v2);
        }
        return;
    }

    // ---- block 0: control word + question path ----
    if (tid == 0) { ((int*)ws)[0] = bf; }

    for (int i = tid; i < 900; i += 256) QE[i] = ldx(qe_in, i, bf);
    if (tid < 30) IDF[tid] = ldx(qidf_in, tid, bf);
    for (int i = tid; i < 2700; i += 256) W[i] = ldx(w1_in, i, bf);
    __syncthreads();

    for (int idx = tid; idx < 900; idx += 256) {
        int s = idx / 30, o = idx % 30;
        float acc = ldx(b1_in, o, bf);
        for (int k = 0; k < 3; ++k) {
            int t = s + k - 1;
            if (t < 0 || t >= 30) continue;
            for (int i = 0; i < 30; ++i) acc += QE[t*30 + i] * W[o*90 + i*3 + k];
        }
        acc = acc >= 0.f ? acc : SLOPE * acc;
        T1[idx] = acc + QE[idx];
    }
    __syncthreads();
    for (int i = tid; i < 2700; i += 256) W[i] = ldx(w2_in, i, bf);
    __syncthreads();
    for (int idx = tid; idx < 900; idx += 256) {
        int s = idx / 30, o = idx % 30;
        float acc = ldx(b2_in, o, bf);
        for (int k = 0; k < 3; ++k) {
            int t = s + k - 1;
            if (t < 0 || t >= 30) continue;
            for (int i = 0; i < 30; ++i) acc += T1[t*30 + i] * W[o*90 + i*3 + k];
        }
        acc = acc >= 0.f ? acc : SLOPE * acc;
        QC[idx] = acc + T1[idx];
    }
    __syncthreads();

    if (tid < 30) {
        float s1 = 0.f, s2 = 0.f;
        for (int d = 0; d < 30; ++d) {
            float a = QE[tid*30 + d]; s1 += a*a;
            float b = QC[tid*30 + d]; s2 += b*b;
        }
        float n1 = sqrtf(s1);
        ws[OFF_QNN + tid] = n1;
        ws[OFF_QNI + tid] = 1.0f / n1;
        ws[OFF_QNS + tid] = 1.0f / sqrtf(s2);
        float z = ldx(qwb_in, 0, bf);
        for (int d = 0; d < 30; ++d) z += QC[tid*30 + d] * ldx(qwW_in, d, bf);
        z += IDF[tid] * ldx(qwW_in, 30, bf);
        LG[tid] = z;
    }
    __syncthreads();
    if (tid == 0) {
        float m = -1e30f;
        for (int q = 0; q < 30; ++q) m = fmaxf(m, LG[q]);
        float sum = 0.f, e[30];
        for (int q = 0; q < 30; ++q) { e[q] = expf(LG[q] - m); sum += e[q]; }
        for (int q = 0; q < 30; ++q) ws[OFF_QW + q] = e[q] / sum;
    }
    for (int i = tid; i < 1024; i += 256) {
        int q = i >> 5, d = i & 31;
        float ve = (q < 30 && d < 30) ? QE[q*30 + d] : 0.f;
        float vc = (q < 30 && d < 30) ? QC[q*30 + d] : 0.f;
        wsu[U16_QEA + i] = f2bf(ve);
        wsu[U16_QCA + i] = f2bf(vc);
    }
}

// ---------------- kernel 2: one WAVE per sentence, zero barriers ----------------
// X layout: 103 rows x 16 dwords (row R at dword 16R; dword 15 of each row = zero pad).
// Stored row R = input row R-1; rows 0,101,102 all-zero. All fragment accesses are
// aligned ds_read_b128. Conv runs IN PLACE with a one-tile-ahead fragment pre-read
// (only cross-tile alias is row 16mt+16) fenced by s_waitcnt lgkmcnt(0).
__global__ __launch_bounds__(128, 5) void k_main(const void* doc_in, const void* gaf_in,
                                                 void* out, float* ws) {
    const int tid = threadIdx.x;
    const int lane = tid & 63;
    const int wid = tid >> 6;
    const int n = blockIdx.x * 2 + wid;
    const int bf = ((const int*)ws)[0];
    const int l15 = lane & 15;
    const int quad = lane >> 4;

    __shared__ __align__(16) uint Xs[2][1648];
    __shared__ __align__(16) float INVXs[2][112];
    __shared__ float FEs[2][30][6];

    uint* X = Xs[wid];
    uint4* X4 = (uint4*)X;
    float* INVX = INVXs[wid];
    float (*FE)[6] = FEs[wid];

    const ushort* wsu = (const ushort*)ws;
    const uint4* qeA = (const uint4*)(wsu + U16_QEA);
    const uint4* qcA = (const uint4*)(wsu + U16_QCA);
    const uint4* wb1 = (const uint4*)(wsu + U16_WB1);
    const uint4* wb2 = (const uint4*)(wsu + U16_WB2);

    // prefetch gaf scalars (consumed at the very end by lane 0)
    float ga0 = ldx(gaf_in, (long)n*3 + 0, bf);
    float ga1 = ldx(gaf_in, (long)n*3 + 1, bf);
    float ga2 = ldx(gaf_in, (long)n*3 + 2, bf);

    // ---- P0: zero pads + fused load+row-norm ----
    {
        uint4 z4 = make_uint4(0u, 0u, 0u, 0u);
        if (lane < 12) X4[(lane < 4) ? lane : (400 + lane)] = z4;   // rows 0,101,102
        if (lane >= 12 && lane < 24) INVX[100 + (lane - 12)] = 0.f; // INVX pad
    }
    // 4 lanes per row-granule; 400 granules; norms fused via 2-shfl reduce.
    for (int g = lane; g < 400; g += 64) {
        int r = g >> 2, t = g & 3;
        uint4 w;
        float s2;
        if (bf) {
            const uint* gp = (const uint*)doc_in + (size_t)n * 1500 + r * 15 + t * 4;
            uint a = gp[0], b = gp[1], c = gp[2];
            uint d = (t < 3) ? gp[3] : 0u;
            w = make_uint4(a, b, c, d);
            float x0 = blo(a), x1 = bhi(a), x2 = blo(b), x3 = bhi(b);
            float x4 = blo(c), x5 = bhi(c), x6 = blo(d), x7 = bhi(d);
            s2 = x0*x0 + x1*x1 + x2*x2 + x3*x3 + x4*x4 + x5*x5 + x6*x6 + x7*x7;
        } else {
            const float* p = (const float*)doc_in + (size_t)n * 3000 + r * 30 + t * 8;
            float2 f0 = ((const float2*)p)[0];
            float2 f1 = ((const float2*)p)[1];
            float2 f2 = ((const float2*)p)[2];
            float2 f3 = (t < 3) ? ((const float2*)p)[3] : make_float2(0.f, 0.f);
            w = make_uint4(pk2(f0.x, f0.y), pk2(f1.x, f1.y), pk2(f2.x, f2.y), pk2(f3.x, f3.y));
            s2 = f0.x*f0.x + f0.y*f0.y + f1.x*f1.x + f1.y*f1.y
               + f2.x*f2.x + f2.y*f2.y + f3.x*f3.x + f3.y*f3.y;
        }
        X4[(r + 1) * 4 + t] = w;
        s2 += __shfl_xor(s2, 1);
        s2 += __shfl_xor(s2, 2);
        if (t == 0) INVX[r] = 1.f / sqrtf(s2);
    }
    LGKM0();   // X + INVX committed before any cross-lane read

    // transposed sim + in-lane pool; lane owns q = qbase + l15
    auto sim_pool = [&](const uint4* qa, int iqOff, int fbase, bool do_oh, int qbase) {
        const int q = qbase + l15;
        Frag b;
        b.u4 = qa[q * 4 + quad];            // B[k=quad*8+j][n=q] == Q[q][k] table row
        f32x4 acc[7];
        #pragma unroll
        for (int mt = 0; mt < 7; ++mt) {
            int m = mt * 16 + l15;          // s-row of A
            Frag a;
            if (m < 100) a.u4 = X4[(m + 1) * 4 + quad];
            else         a.u4 = make_uint4(0u, 0u, 0u, 0u);
            f32x4 z = {0.f, 0.f, 0.f, 0.f};
            acc[mt] = __builtin_amdgcn_mfma_f32_16x16x32_bf16(a.v, b.v, z, 0, 0, 0);
        }
        // u[s] = num * invx[s]; s = mt*16 + quad*4 + r (in-lane)
        const float4* INVX4 = (const float4*)INVX;
        float thr = (do_oh && q < 30) ? 0.999f * ws[OFF_QNN + q] : 1e30f;
        float iq  = (q < 30) ? ws[iqOff + q] : 0.f;
        float g[7][4];
        int cnt = 0;
        #pragma unroll
        for (int mt = 0; mt < 7; ++mt) {
            float4 ix = INVX4[mt * 4 + quad];
            float ixa[4] = {ix.x, ix.y, ix.z, ix.w};
            #pragma unroll
            for (int r = 0; r < 4; ++r) {
                float u = acc[mt][r] * ixa[r];
                if (mt == 6 && (quad * 4 + r) >= 4) u = -1e30f;   // s >= 100
                g[mt][r] = u;
                if (do_oh) cnt += (u > thr) ? 1 : 0;
            }
        }
        // in-lane top5-of-28: 7x sort4 + capped merge tree
        #pragma unroll
        for (int mt = 0; mt < 7; ++mt) sort4d(g[mt][0], g[mt][1], g[mt][2], g[mt][3]);
        float p0[5], p1[5], p2[5], q0[5], q1[5], t[5];
        merge44_5(g[0], g[1], p0);
        merge44_5(g[2], g[3], p1);
        merge44_5(g[4], g[5], p2);
        merge55_5(p0, p1, q0);
        merge54_5(p2, g[6], q1);
        merge55_5(q0, q1, t);
        // butterfly across the 4 quads (lanes xor 16, 32; l15 preserved)
        #pragma unroll
        for (int d = 16; d < 64; d <<= 1) {
            float pp[5];
            pp[0] = __shfl_xor(t[0], d); pp[1] = __shfl_xor(t[1], d);
            pp[2] = __shfl_xor(t[2], d); pp[3] = __shfl_xor(t[3], d);
            pp[4] = __shfl_xor(t[4], d);
            if (do_oh) cnt += __shfl_xor(cnt, d);
            float tn[5];
            merge55_5(t, pp, tn);
            t[0] = tn[0]; t[1] = tn[1]; t[2] = tn[2]; t[3] = tn[3]; t[4] = tn[4];
        }
        if (quad == 0 && q < 30) {
            if (do_oh) {
                FE[q][0] = cnt > 0 ? 1.f : 0.f;
                FE[q][1] = (float)(cnt > 5 ? 5 : cnt) * 0.2f;
            }
            FE[q][fbase]     = t[0] * iq;
            FE[q][fbase + 1] = (t[0] + t[1] + t[2] + t[3] + t[4]) * 0.2f * iq;
        }
    };

    // in-place conv over all 7 tiles (this wave), one-tile-ahead pre-read
    auto conv_inplace = [&](const uint4* wb, int bOff, bool donorm) {
        Frag wf0[3], wf1[3];
        #pragma unroll
        for (int k = 0; k < 3; ++k) {
            wf0[k].u4 = wb[l15 * 12 + k * 4 + quad];          // o-tile 0 rows
            wf1[k].u4 = wb[(16 + l15) * 12 + k * 4 + quad];   // o-tile 1 rows (30,31 zero)
        }
        float b40[4], b41[4];
        #pragma unroll
        for (int r = 0; r < 4; ++r) {
            int o0 = quad * 4 + r, o1 = 16 + o0;
            b40[r] = ws[bOff + o0];
            b41[r] = (o1 < 30) ? ws[bOff + o1] : 0.f;
        }
        auto load_xf = [&](int mt, Frag& f0, Frag& f1, Frag& f2) {
            int s = mt * 16 + l15;
            if (s < 100) {
                f0.u4 = X4[s * 4 + quad];           // window rows R = s, s+1, s+2
                f1.u4 = X4[(s + 1) * 4 + quad];
                f2.u4 = X4[(s + 2) * 4 + quad];
            } else {
                f0.u4 = f1.u4 = f2.u4 = make_uint4(0u, 0u, 0u, 0u);
            }
        };
        Frag xf0, xf1, xf2;
        load_xf(0, xf0, xf1, xf2);
        #pragma unroll
        for (int mt = 0; mt < 7; ++mt) {
            const int s = mt * 16 + l15;
            const bool sv = (s < 100);
            const int db = (s + 1) * 16 + quad * 2;
            uint u0 = 0u, u1 = 0u, u2 = 0u, u3 = 0u;
            if (sv) {
                uint2 ua = *(const uint2*)(X + db);
                uint2 ub = *(const uint2*)(X + db + 8);
                u0 = ua.x; u1 = ua.y; u2 = ub.x; u3 = ub.y;
            }
            Frag xn0, xn1, xn2;
            if (mt < 6) load_xf(mt + 1, xn0, xn1, xn2);
            f32x4 a0 = {0.f, 0.f, 0.f, 0.f}, a1 = {0.f, 0.f, 0.f, 0.f};
            a0 = __builtin_amdgcn_mfma_f32_16x16x32_bf16(wf0[0].v, xf0.v, a0, 0, 0, 0);
            a1 = __builtin_amdgcn_mfma_f32_16x16x32_bf16(wf1[0].v, xf0.v, a1, 0, 0, 0);
            a0 = __builtin_amdgcn_mfma_f32_16x16x32_bf16(wf0[1].v, xf1.v, a0, 0, 0, 0);
            a1 = __builtin_amdgcn_mfma_f32_16x16x32_bf16(wf1[1].v, xf1.v, a1, 0, 0, 0);
            a0 = __builtin_amdgcn_mfma_f32_16x16x32_bf16(wf0[2].v, xf2.v, a0, 0, 0, 0);
            a1 = __builtin_amdgcn_mfma_f32_16x16x32_bf16(wf1[2].v, xf2.v, a1, 0, 0, 0);
            LGKM0();   // pre-reads + residuals landed; safe to overwrite
            float ss = 0.f;
            if (sv) {
                float v0 = lk(a0[0] + b40[0]) + blo(u0);
                float v1 = lk(a0[1] + b40[1]) + bhi(u0);
                float v2 = lk(a0[2] + b40[2]) + blo(u1);
                float v3 = lk(a0[3] + b40[3]) + bhi(u1);
                *(uint2*)(X + db) = make_uint2(pk2(v0, v1), pk2(v2, v3));
                float w0 = lk(a1[0] + b41[0]) + blo(u2);
                float w1 = lk(a1[1] + b41[1]) + bhi(u2);
                ss = v0*v0 + v1*v1 + v2*v2 + v3*v3 + w0*w0 + w1*w1;
                if (quad < 3) {
                    float w2 = lk(a1[2] + b41[2]) + blo(u3);
                    float w3 = lk(a1[3] + b41[3]) + bhi(u3);
                    *(uint2*)(X + db + 8) = make_uint2(pk2(w0, w1), pk2(w2, w3));
                    ss += w2*w2 + w3*w3;
                } else {
                    X[db + 8] = pk2(w0, w1);   // o=30,31 masked; keep row pad zero
                }
            }
            if (donorm) {                      // fused conv_res row norm
                ss += __shfl_xor(ss, 16);
                ss += __shfl_xor(ss, 32);
                if (quad == 0 && sv) INVX[s] = 1.f / sqrtf(ss);
            }
            xf0 = xn0; xf1 = xn1; xf2 = xn2;
        }
    };

    // ---- P2: sim_insens (both q halves) on original X ----
    sim_pool(qeA, OFF_QNI, 2, true, 0);
    sim_pool(qeA, OFF_QNI, 2, true, 16);

    // ---- P3: conv1 in place ----
    conv_inplace(wb1, OFF_B1, false);
    LGKM0();
    // ---- P4: conv2 in place, fused row norms ----
    conv_inplace(wb2, OFF_B2, true);
    LGKM0();

    // ---- P5: sim_sens (both q halves) ----
    sim_pool(qcA, OFF_QNS, 4, false, 0);
    sim_pool(qcA, OFF_QNS, 4, false, 16);
    LGKM0();

    // ---- P6: per-q MLP, butterfly-sum, score write ----
    float val = 0.f;
    if (lane < 30) {
        float lo = ws[OFF_LQ2B];
        #pragma unroll
        for (int j = 0; j < 8; ++j) {
            float h = ws[OFF_LQ1B + j];
            #pragma unroll
            for (int f = 0; f < 6; ++f) h += FE[lane][f] * ws[OFF_LQ1W + j*6 + f];
            h = lk(h);
            lo += h * ws[OFF_LQ2W + j];
        }
        val = lo * ws[OFF_QW + lane];
    }
    #pragma unroll
    for (int d = 32; d >= 1; d >>= 1) val += __shfl_xor(val, d);
    if (lane == 0) {
        float emit = val * (1.f / 30.f);
        float z = ws[OFF_SOB];
        z += ga0 * ws[OFF_SOW + 0];
        z += ga1 * ws[OFF_SOW + 1];
        z += ga2 * ws[OFF_SOW + 2];
        z += emit * ws[OFF_SOW + 3];
        float sc = 1.f / (1.f + expf(-z));
        if (bf) ((__hip_bfloat16*)out)[1 + n] = __float2bfloat16(sc);
        else    ((float*)out)[1 + n] = sc;
    }
}

// ---------------- kernel 3: doc-level head ----------------
__global__ __launch_bounds__(256) void k_final(const void* docgaf_in, void* out, const float* ws) {
    const int tid = threadIdx.x;
    const int bf = ((const int*)ws)[0];
    __shared__ float red[256];
    float m = -1e30f;
    for (int i = tid; i < 4000; i += 256) {
        float v = bf ? __bfloat162float(((const __hip_bfloat16*)out)[1 + i])
                     : ((const float*)out)[1 + i];
        m = fmaxf(m, v);
    }
    red[tid] = m;
    __syncthreads();
    for (int off = 128; off > 0; off >>= 1) {
        if (tid < off) red[tid] = fmaxf(red[tid], red[tid + off]);
        __syncthreads();
    }
    if (tid == 0) {
        float f = ws[OFF_FLB] + red[0] * ws[OFF_FLW + 0];
        for (int i = 0; i < 4; ++i) f += ldx(docgaf_in, i, bf) * ws[OFF_FLW + 1 + i];
        if (bf) ((__hip_bfloat16*)out)[0] = __float2bfloat16(f);
        else    ((float*)out)[0] = f;
    }
}

extern "C" void kernel_launch(void* const* d_in, const int* in_sizes, int n_in,
                              void* d_out, int out_size, void* d_ws, size_t ws_size,
                              hipStream_t stream) {
    float* ws = (float*)d_ws;
    k_prep<<<3, 256, 0, stream>>>(d_in[0], d_in[2], d_in[3], d_in[5], d_in[6], d_in[7], d_in[8],
                                  d_in[9], d_in[10], d_in[11], d_in[12], d_in[13], d_in[14],
                                  d_in[15], d_in[16], d_in[17], d_in[18], ws);
    k_main<<<2000, 128, 0, stream>>>(d_in[0], d_in[1], d_out, ws);
    k_final<<<1, 256, 0, stream>>>(d_in[4], d_out, ws);
}

// Round 3
// 174.868 us; speedup vs baseline: 1.0240x; 1.0240x over previous
//
#include <hip/hip_runtime.h>
#include <hip/hip_bf16.h>

#define SLOPE 0.1f

// ---- ws int-index layout: [0]=bf flag ----
// ---- ws float-index layout ----
#define OFF_QW    1816    // 30   q_weights (softmax)
#define OFF_QNI   1846    // 30   1/||question_embeds[q]||
#define OFF_QNS   1876    // 30   1/||q_conv[q]||
#define OFF_QNN   1906    // 30   ||question_embeds[q]|| (raw norm, for one-hot thr)
#define OFF_B1    4606    // 30
#define OFF_B2    7336    // 30
#define OFF_LQ1W  7366    // 48
#define OFF_LQ1B  7414    // 8
#define OFF_LQ2W  7422    // 8
#define OFF_LQ2B  7430    // 1
#define OFF_SOW   7431    // 4
#define OFF_SOB   7435    // 1
#define OFF_FLW   7436    // 5
#define OFF_FLB   7441    // 1
// ---- bf16 (u16-index) region, starts at byte 32768 ----
#define U16_QEA   16384   // 32 rows x 32  (B-operand QE, zeros at d>=30, q>=30)
#define U16_QCA   17408   // 32 rows x 32  (B-operand QC)
#define U16_WB1   18432   // 32 rows x 96  (W1[o][kk'], kk'=k*32+i, zeros i>=30)
#define U16_WB2   21504   // 32 rows x 96

// X LDS layout: 15 dwords (30 bf16) per stored row; stored row R = input row R-1.
// rows 0,101,102 zero. rows 103/104 = mirror of stored rows 48/49 (original X),
// rows 105/106 = mirror of stored rows 48/49 (conv1 output). dwords 1605+ zero pad.
#define XDW 1620

typedef __attribute__((ext_vector_type(8))) __bf16 bf16x8;
typedef __attribute__((ext_vector_type(4))) float f32x4;

union Frag { uint4 u4; uint u[4]; bf16x8 v; };

__device__ __forceinline__ float bf2f(ushort h) {
    union { uint u; float f; } c; c.u = ((uint)h) << 16; return c.f;
}
__device__ __forceinline__ ushort f2bf(float f) {   // RNE, finite inputs
    union { float f; uint u; } c; c.f = f;
    uint u = c.u;
    return (ushort)((u + 0x7FFFu + ((u >> 16) & 1u)) >> 16);
}
__device__ __forceinline__ float ldx(const void* p, long i, int bf) {
    if (bf) return bf2f(((const ushort*)p)[i]);
    return ((const float*)p)[i];
}
// pack two f32 -> one dword of 2x bf16 (RNE), single instruction on gfx950
__device__ __forceinline__ uint pk2(float lo, float hi) {
    uint r;
    asm("v_cvt_pk_bf16_f32 %0, %1, %2" : "=v"(r) : "v"(lo), "v"(hi));
    return r;
}
__device__ __forceinline__ float blo(uint u) { return __uint_as_float(u << 16); }
__device__ __forceinline__ float bhi(uint u) { return __uint_as_float(u & 0xFFFF0000u); }
__device__ __forceinline__ float lk(float x) { return fmaxf(x, SLOPE * x); }  // leaky, SLOPE<1

#define CE(x, y) { float _hi = fmaxf(x, y), _lo = fminf(x, y); x = _hi; y = _lo; }

__device__ __forceinline__ void sort4d(float& a, float& b, float& c, float& d) {
    CE(a, b); CE(c, d); CE(a, c); CE(b, d); CE(b, c);
}
// merge two sorted-desc 4-lists -> top5 desc
__device__ __forceinline__ void merge44_5(const float* a, const float* b, float* t) {
    t[0] = fmaxf(a[0], b[0]);
    t[1] = fmaxf(fminf(a[0], b[0]), fmaxf(a[1], b[1]));
    t[2] = fmaxf(fmaxf(fminf(a[0], b[1]), fminf(a[1], b[0])), fmaxf(a[2], b[2]));
    t[3] = fmaxf(fmaxf(fminf(a[0], b[2]), fminf(a[1], b[1])),
                 fmaxf(fminf(a[2], b[0]), fmaxf(a[3], b[3])));
    t[4] = fmaxf(fmaxf(fminf(a[0], b[3]), fminf(a[1], b[2])),
                 fmaxf(fminf(a[2], b[1]), fminf(a[3], b[0])));
}
// merge sorted5 + sorted4 -> top5
__device__ __forceinline__ void merge54_5(const float* a, const float* b, float* t) {
    t[0] = fmaxf(a[0], b[0]);
    t[1] = fmaxf(fminf(a[0], b[0]), fmaxf(a[1], b[1]));
    t[2] = fmaxf(fmaxf(fminf(a[0], b[1]), fminf(a[1], b[0])), fmaxf(a[2], b[2]));
    t[3] = fmaxf(fmaxf(fminf(a[0], b[2]), fminf(a[1], b[1])),
                 fmaxf(fminf(a[2], b[0]), fmaxf(a[3], b[3])));
    t[4] = fmaxf(fmaxf(fmaxf(fminf(a[0], b[3]), fminf(a[1], b[2])),
                       fmaxf(fminf(a[2], b[1]), fminf(a[3], b[0]))), a[4]);
}
// merge two sorted5 -> top5
__device__ __forceinline__ void merge55_5(const float* a, const float* b, float* t) {
    t[0] = fmaxf(a[0], b[0]);
    t[1] = fmaxf(fminf(a[0], b[0]), fmaxf(a[1], b[1]));
    t[2] = fmaxf(fmaxf(fminf(a[0], b[1]), fminf(a[1], b[0])), fmaxf(a[2], b[2]));
    t[3] = fmaxf(fmaxf(fminf(a[0], b[2]), fminf(a[1], b[1])),
                 fmaxf(fminf(a[2], b[0]), fmaxf(a[3], b[3])));
    t[4] = fmaxf(fmaxf(fmaxf(fminf(a[0], b[3]), fminf(a[1], b[2])),
                       fmaxf(fminf(a[2], b[1]), fminf(a[3], b[0]))),
                 fmaxf(a[4], b[4]));
}

// dtype detection: f32 mantissa words carry wild bf16-exponent fields
__device__ __forceinline__ int detect_bf(const void* doc_in, int tid, int* scnt) {
    if (tid == 0) *scnt = 0;
    __syncthreads();
    const ushort* p = (const ushort*)doc_in;
    int local = 0;
    for (int i = tid; i < 4096; i += 256) {
        unsigned e = (p[i] >> 7) & 0xFFu;
        if (e != 0u && (e < 100u || e > 134u)) local++;
    }
    atomicAdd(scnt, local);
    __syncthreads();
    return (*scnt > 200) ? 0 : 1;
}

// ---------------- kernel 1 (3 blocks): detect + question path + repack ----------------
__global__ __launch_bounds__(256) void k_prep(
        const void* doc_in,
        const void* qe_in, const void* qidf_in,
        const void* w1_in, const void* b1_in,
        const void* w2_in, const void* b2_in,
        const void* qwW_in, const void* qwb_in,
        const void* lq1W_in, const void* lq1b_in,
        const void* lq2W_in, const void* lq2b_in,
        const void* soW_in, const void* sob_in,
        const void* flW_in, const void* flb_in,
        float* ws) {
    const int tid = threadIdx.x;
    const int blk = blockIdx.x;
    __shared__ float QE[900], T1[900], QC[900], W[2700], IDF[32], LG[32];
    __shared__ int scnt;

    const int bf = detect_bf(doc_in, tid, &scnt);
    ushort* wsu = (ushort*)ws;

    if (blk == 1) {
        if (tid == 0) { ((int*)ws)[0] = bf; }
        if (tid < 30) ws[OFF_B1 + tid] = ldx(b1_in, tid, bf);
        if (tid < 48) ws[OFF_LQ1W + tid] = ldx(lq1W_in, tid, bf);
        if (tid < 8)  { ws[OFF_LQ1B + tid] = ldx(lq1b_in, tid, bf);
                        ws[OFF_LQ2W + tid] = ldx(lq2W_in, tid, bf); }
        if (tid < 4)  ws[OFF_SOW + tid] = ldx(soW_in, tid, bf);
        if (tid < 5)  ws[OFF_FLW + tid] = ldx(flW_in, tid, bf);
        if (tid == 1) { ws[OFF_LQ2B] = ldx(lq2b_in, 0, bf);
                        ws[OFF_SOB]  = ldx(sob_in, 0, bf);
                        ws[OFF_FLB]  = ldx(flb_in, 0, bf); }
        for (int i = tid; i < 3072; i += 256) {
            int o = i / 96, kk = i % 96;
            int k = kk >> 5, ii = kk & 31;      // kk' = k*32 + i, zeros at i>=30
            float v1 = 0.f;
            if (o < 30 && ii < 30) v1 = ldx(w1_in, (long)o*90 + ii*3 + k, bf);
            wsu[U16_WB1 + i] = f2bf(v1);
        }
        return;
    }
    if (blk == 2) {
        if (tid < 30) ws[OFF_B2 + tid] = ldx(b2_in, tid, bf);
        for (int i = tid; i < 3072; i += 256) {
            int o = i / 96, kk = i % 96;
            int k = kk >> 5, ii = kk & 31;
            float v2 = 0.f;
            if (o < 30 && ii < 30) v2 = ldx(w2_in, (long)o*90 + ii*3 + k, bf);
            wsu[U16_WB2 + i] = f2bf(v2);
        }
        return;
    }

    // ---- block 0: control word + question path ----
    if (tid == 0) { ((int*)ws)[0] = bf; }

    for (int i = tid; i < 900; i += 256) QE[i] = ldx(qe_in, i, bf);
    if (tid < 30) IDF[tid] = ldx(qidf_in, tid, bf);
    for (int i = tid; i < 2700; i += 256) W[i] = ldx(w1_in, i, bf);
    __syncthreads();

    for (int idx = tid; idx < 900; idx += 256) {
        int s = idx / 30, o = idx % 30;
        float acc = ldx(b1_in, o, bf);
        for (int k = 0; k < 3; ++k) {
            int t = s + k - 1;
            if (t < 0 || t >= 30) continue;
            for (int i = 0; i < 30; ++i) acc += QE[t*30 + i] * W[o*90 + i*3 + k];
        }
        acc = acc >= 0.f ? acc : SLOPE * acc;
        T1[idx] = acc + QE[idx];
    }
    __syncthreads();
    for (int i = tid; i < 2700; i += 256) W[i] = ldx(w2_in, i, bf);
    __syncthreads();
    for (int idx = tid; idx < 900; idx += 256) {
        int s = idx / 30, o = idx % 30;
        float acc = ldx(b2_in, o, bf);
        for (int k = 0; k < 3; ++k) {
            int t = s + k - 1;
            if (t < 0 || t >= 30) continue;
            for (int i = 0; i < 30; ++i) acc += T1[t*30 + i] * W[o*90 + i*3 + k];
        }
        acc = acc >= 0.f ? acc : SLOPE * acc;
        QC[idx] = acc + T1[idx];
    }
    __syncthreads();

    if (tid < 30) {
        float s1 = 0.f, s2 = 0.f;
        for (int d = 0; d < 30; ++d) {
            float a = QE[tid*30 + d]; s1 += a*a;
            float b = QC[tid*30 + d]; s2 += b*b;
        }
        float n1 = sqrtf(s1);
        ws[OFF_QNN + tid] = n1;
        ws[OFF_QNI + tid] = 1.0f / n1;
        ws[OFF_QNS + tid] = 1.0f / sqrtf(s2);
        float z = ldx(qwb_in, 0, bf);
        for (int d = 0; d < 30; ++d) z += QC[tid*30 + d] * ldx(qwW_in, d, bf);
        z += IDF[tid] * ldx(qwW_in, 30, bf);
        LG[tid] = z;
    }
    __syncthreads();
    if (tid == 0) {
        float m = -1e30f;
        for (int q = 0; q < 30; ++q) m = fmaxf(m, LG[q]);
        float sum = 0.f, e[30];
        for (int q = 0; q < 30; ++q) { e[q] = expf(LG[q] - m); sum += e[q]; }
        for (int q = 0; q < 30; ++q) ws[OFF_QW + q] = e[q] / sum;
    }
    for (int i = tid; i < 1024; i += 256) {
        int q = i >> 5, d = i & 31;
        float ve = (q < 30 && d < 30) ? QE[q*30 + d] : 0.f;
        float vc = (q < 30 && d < 30) ? QC[q*30 + d] : 0.f;
        wsu[U16_QEA + i] = f2bf(ve);
        wsu[U16_QCA + i] = f2bf(vc);
    }
}

// ---------------- kernel 2: per-sentence fused MFMA pipeline (in-place conv) --------
// 2 waves/block, one sentence/block. Conv is in-place on X:
//  - wave0 owns tiles 0..2 (writes stored rows 1..48), wave1 owns tiles 3..6 (49..100)
//  - ascending tiles + pre-read of next tile's f0 before this tile's stores
//    (only overlap row is 16mt+16; DS ops complete in-order per wave)
//  - cross-wave boundary rows 48/49 are read from mirror rows:
//    conv1 reads 103/104 (original X, copied in P1); conv1's boundary lanes also
//    duplicate their output rows into 105/106, which conv2 reads after the barrier.
__global__ __launch_bounds__(128, 5) void k_main(const void* doc_in, const void* gaf_in,
                                                 void* out, float* ws) {
    const int n = blockIdx.x;
    const int tid = threadIdx.x;
    const int bf = ((const int*)ws)[0];
    const int lane = tid & 63;
    const int wid = tid >> 6;          // 0 or 1
    const int l15 = lane & 15;
    const int quad = lane >> 4;

    __shared__ __align__(16) uint X[XDW];
    __shared__ __align__(16) float INVX[112];   // [100,112) zero pad
    __shared__ float FE[30][6];

    const ushort* wsu = (const ushort*)ws;
    const uint4* qeA = (const uint4*)(wsu + U16_QEA);
    const uint4* qcA = (const uint4*)(wsu + U16_QCA);
    const uint4* wb1 = (const uint4*)(wsu + U16_WB1);
    const uint4* wb2 = (const uint4*)(wsu + U16_WB2);

    // prefetch gaf scalars (consumed at the very end by wave0 lane0)
    float ga0 = ldx(gaf_in, (long)n*3 + 0, bf);
    float ga1 = ldx(gaf_in, (long)n*3 + 1, bf);
    float ga2 = ldx(gaf_in, (long)n*3 + 2, bf);

    // ---- P0: zero pads + vectorized load ----
    if (tid < 60) {   // rows 0,101,102 + tail pad dwords [1605,1620)
        int j = (tid < 15) ? tid : ((tid < 45) ? (1500 + tid) : (1560 + tid));
        X[j] = 0u;
    }
    if (tid >= 100 && tid < 112) INVX[tid] = 0.f;
    if (bf) {
        const uint4* g = (const uint4*)((const ushort*)doc_in + (size_t)n * 3000);
        for (int j = tid; j < 375; j += 128) {
            uint4 v = g[j];
            int d = 15 + 4 * j;
            X[d] = v.x; X[d + 1] = v.y; X[d + 2] = v.z; X[d + 3] = v.w;
        }
    } else {
        const float4* p4 = (const float4*)((const float*)doc_in + (size_t)n * 3000);
        for (int j = tid; j < 750; j += 128) {
            float4 f = p4[j];
            int d = 15 + 2 * j;
            X[d]     = pk2(f.x, f.y);
            X[d + 1] = pk2(f.z, f.w);
        }
    }
    __syncthreads();   // B1

    // ---- P1: inverse row norms of X + original-X boundary mirrors ----
    if (tid < 100) {
        const uint* r = X + (tid + 1) * 15;
        float s = 0.f;
        #pragma unroll
        for (int i = 0; i < 15; ++i) {
            uint u = r[i];
            float lo = __uint_as_float(u << 16);
            float hi = __uint_as_float(u & 0xFFFF0000u);
            s += lo * lo + hi * hi;
        }
        INVX[tid] = 1.f / sqrtf(s);
    } else if (tid < 115) {
        X[103*15 + (tid - 100)] = X[48*15 + (tid - 100)];   // mirror orig row 48
    } else if (tid < 128 + 2) { /* nothing */ }
    if (tid >= 100 && tid < 115) { /* handled above */ }
    if (tid < 15 || true) { /* no-op to keep structure simple */ }
    if (tid >= 113 && tid < 128) {
        X[104*15 + (tid - 113)] = X[49*15 + (tid - 113)];   // mirror orig row 49
    }
    __syncthreads();   // B2

    // transposed sim + in-lane pool; lane owns q = wid*16 + l15
    auto sim_pool = [&](const uint4* qa, int iqOff, int fbase, bool do_oh) {
        const int q = wid * 16 + l15;
        Frag b;
        b.u4 = qa[q * 4 + quad];            // B[k=quad*8+j][n=q] == Q[q][k] table row
        f32x4 acc[7];
        #pragma unroll
        for (int mt = 0; mt < 7; ++mt) {
            int m = mt * 16 + l15;          // s-row of A
            Frag a;
            if (m < 100) {
                int base = (m + 1) * 15 + quad * 4;
                a.u[0] = X[base];     a.u[1] = X[base + 1];
                a.u[2] = X[base + 2]; a.u[3] = X[base + 3];
            } else { a.u[0] = a.u[1] = a.u[2] = a.u[3] = 0u; }
            f32x4 z = {0.f, 0.f, 0.f, 0.f};
            acc[mt] = __builtin_amdgcn_mfma_f32_16x16x32_bf16(a.v, b.v, z, 0, 0, 0);
        }
        // u[s] = num * invx[s]; s = mt*16 + quad*4 + r (in-lane)
        const float4* INVX4 = (const float4*)INVX;
        float thr = (do_oh && q < 30) ? 0.999f * ws[OFF_QNN + q] : 1e30f;
        float iq  = (q < 30) ? ws[iqOff + q] : 0.f;
        float g[7][4];
        int cnt = 0;
        #pragma unroll
        for (int mt = 0; mt < 7; ++mt) {
            float4 ix = INVX4[mt * 4 + quad];
            float ixa[4] = {ix.x, ix.y, ix.z, ix.w};
            #pragma unroll
            for (int r = 0; r < 4; ++r) {
                float u = acc[mt][r] * ixa[r];
                if (mt == 6 && (quad * 4 + r) >= 4) u = -1e30f;   // s >= 100
                g[mt][r] = u;
                if (do_oh) cnt += (u > thr) ? 1 : 0;
            }
        }
        // in-lane top5-of-28: 7x sort4 + capped merge tree
        #pragma unroll
        for (int mt = 0; mt < 7; ++mt) sort4d(g[mt][0], g[mt][1], g[mt][2], g[mt][3]);
        float p0[5], p1[5], p2[5], q0[5], q1[5], t[5];
        merge44_5(g[0], g[1], p0);
        merge44_5(g[2], g[3], p1);
        merge44_5(g[4], g[5], p2);
        merge55_5(p0, p1, q0);
        merge54_5(p2, g[6], q1);
        merge55_5(q0, q1, t);
        // butterfly across the 4 quads (lanes xor 16, 32; l15 preserved)
        #pragma unroll
        for (int d = 16; d < 64; d <<= 1) {
            float pp[5];
            pp[0] = __shfl_xor(t[0], d); pp[1] = __shfl_xor(t[1], d);
            pp[2] = __shfl_xor(t[2], d); pp[3] = __shfl_xor(t[3], d);
            pp[4] = __shfl_xor(t[4], d);
            if (do_oh) cnt += __shfl_xor(cnt, d);
            float tn[5];
            merge55_5(t, pp, tn);
            t[0] = tn[0]; t[1] = tn[1]; t[2] = tn[2]; t[3] = tn[3]; t[4] = tn[4];
        }
        if (quad == 0 && q < 30) {
            if (do_oh) {
                FE[q][0] = cnt > 0 ? 1.f : 0.f;
                FE[q][1] = (float)(cnt > 5 ? 5 : cnt) * 0.2f;
            }
            FE[q][fbase]     = t[0] * iq;
            FE[q][fbase + 1] = (t[0] + t[1] + t[2] + t[3] + t[4]) * 0.2f * iq;
        }
    };

    // in-place conv; wave0 tiles 0..2, wave1 tiles 3..6; f0_next pre-read; mirrors.
    auto conv_inplace = [&](const uint4* wb, int bOff, int mirIn48, int mirIn49,
                            bool dupOut, bool donorm) {
        const int mtb = wid ? 3 : 0;
        const int mte = wid ? 6 : 2;
        Frag wf0[3], wf1[3];
        #pragma unroll
        for (int k = 0; k < 3; ++k) {
            wf0[k].u4 = wb[l15 * 12 + k * 4 + quad];          // o-tile 0 rows
            wf1[k].u4 = wb[(16 + l15) * 12 + k * 4 + quad];   // o-tile 1 rows (30,31 zero)
        }
        float b40[4], b41[4];
        #pragma unroll
        for (int r = 0; r < 4; ++r) {
            int o0 = quad * 4 + r, o1 = 16 + o0;
            b40[r] = ws[bOff + o0];
            b41[r] = (o1 < 30) ? ws[bOff + o1] : 0.f;
        }
        auto load_row = [&](int row) {
            int rr = row;
            if (wid == 1 && row == 48) rr = mirIn48;     // other wave's write range
            if (wid == 0 && row == 49) rr = mirIn49;
            Frag f;
            int base = rr * 15 + quad * 4;
            f.u[0] = X[base];     f.u[1] = X[base + 1];
            f.u[2] = X[base + 2]; f.u[3] = X[base + 3];
            return f;
        };
        Frag zf; zf.u[0] = zf.u[1] = zf.u[2] = zf.u[3] = 0u;
        Frag f0n = (mtb * 16 + l15 < 100) ? load_row(mtb * 16 + l15) : zf;
        for (int mt = mtb; mt <= mte; ++mt) {
            const int s = mt * 16 + l15;
            const bool sv = (s < 100);
            Frag f0 = f0n, f1 = zf, f2 = zf;
            if (sv) { f1 = load_row(s + 1); f2 = load_row(s + 2); }
            // pre-read next tile's f0 BEFORE this tile's stores (row 16mt+16 overlap)
            if (mt < mte) {
                int s2 = (mt + 1) * 16 + l15;
                f0n = (s2 < 100) ? load_row(s2) : zf;
            }
            // residual (own write range, read before store)
            const int db = (s + 1) * 15 + quad * 2;
            uint u0 = 0u, u1 = 0u, u2 = 0u, u3 = 0u;
            if (sv) {
                uint2 ua = *(const uint2*)(X + db);
                uint2 ub = *(const uint2*)(X + db + 8);
                u0 = ua.x; u1 = ua.y; u2 = ub.x; u3 = ub.y;
            }
            f32x4 a0 = {0.f, 0.f, 0.f, 0.f}, a1 = {0.f, 0.f, 0.f, 0.f};
            a0 = __builtin_amdgcn_mfma_f32_16x16x32_bf16(wf0[0].v, f0.v, a0, 0, 0, 0);
            a1 = __builtin_amdgcn_mfma_f32_16x16x32_bf16(wf1[0].v, f0.v, a1, 0, 0, 0);
            a0 = __builtin_amdgcn_mfma_f32_16x16x32_bf16(wf0[1].v, f1.v, a0, 0, 0, 0);
            a1 = __builtin_amdgcn_mfma_f32_16x16x32_bf16(wf1[1].v, f1.v, a1, 0, 0, 0);
            a0 = __builtin_amdgcn_mfma_f32_16x16x32_bf16(wf0[2].v, f2.v, a0, 0, 0, 0);
            a1 = __builtin_amdgcn_mfma_f32_16x16x32_bf16(wf1[2].v, f2.v, a1, 0, 0, 0);
            __builtin_amdgcn_sched_barrier(0);   // pin all reads above the stores
            float ss = 0.f;
            if (sv) {
                float v0 = lk(a0[0] + b40[0]) + blo(u0);
                float v1 = lk(a0[1] + b40[1]) + bhi(u0);
                float v2 = lk(a0[2] + b40[2]) + blo(u1);
                float v3 = lk(a0[3] + b40[3]) + bhi(u1);
                uint s01 = pk2(v0, v1), s23 = pk2(v2, v3);
                *(uint2*)(X + db) = make_uint2(s01, s23);
                float w0 = lk(a1[0] + b41[0]) + blo(u2);
                float w1 = lk(a1[1] + b41[1]) + bhi(u2);
                uint s45 = pk2(w0, w1);
                ss = v0*v0 + v1*v1 + v2*v2 + v3*v3 + w0*w0 + w1*w1;
                uint s67 = 0u;
                if (quad < 3) {
                    float w2 = lk(a1[2] + b41[2]) + blo(u3);
                    float w3 = lk(a1[3] + b41[3]) + bhi(u3);
                    s67 = pk2(w2, w3);
                    *(uint2*)(X + db + 8) = make_uint2(s45, s67);
                    ss += w2*w2 + w3*w3;
                } else {
                    X[db + 8] = s45;   // o=30,31 masked; keep layout
                }
                if (dupOut) {
                    // duplicate boundary output rows into conv1-out mirrors
                    if (wid == 0 && mt == 2 && l15 == 15) {       // row 48 -> 105
                        int mdb = 105*15 + quad*2;
                        *(uint2*)(X + mdb) = make_uint2(s01, s23);
                        if (quad < 3) *(uint2*)(X + mdb + 8) = make_uint2(s45, s67);
                        else          X[mdb + 8] = s45;
                    }
                    if (wid == 1 && mt == 3 && l15 == 0) {        // row 49 -> 106
                        int mdb = 106*15 + quad*2;
                        *(uint2*)(X + mdb) = make_uint2(s01, s23);
                        if (quad < 3) *(uint2*)(X + mdb + 8) = make_uint2(s45, s67);
                        else          X[mdb + 8] = s45;
                    }
                }
            }
            if (donorm) {                      // fused conv_res row norm
                ss += __shfl_xor(ss, 16);
                ss += __shfl_xor(ss, 32);
                if (quad == 0 && sv) INVX[s] = 1.f / sqrtf(ss);
            }
        }
    };

    // ---- P2: sim_insens on original X ----
    sim_pool(qeA, OFF_QNI, 2, true);
    __syncthreads();   // B3 (sim reads X; conv1 writes X in place)

    // ---- P3: conv1 in place (reads orig mirrors 103/104, writes out-mirrors 105/106)
    conv_inplace(wb1, OFF_B1, 103, 104, true, false);
    __syncthreads();   // B4

    // ---- P4: conv2 in place (reads conv1-out mirrors 105/106), fused row norms ----
    conv_inplace(wb2, OFF_B2, 105, 106, false, true);
    __syncthreads();   // B5

    // ---- P5: sim_sens ----
    sim_pool(qcA, OFF_QNS, 4, false);
    __syncthreads();   // B6

    // ---- P6: wave0: per-q MLP, butterfly-sum, score write ----
    if (wid == 0) {
        float val = 0.f;
        if (lane < 30) {
            float lo = ws[OFF_LQ2B];
            #pragma unroll
            for (int j = 0; j < 8; ++j) {
                float h = ws[OFF_LQ1B + j];
                #pragma unroll
                for (int f = 0; f < 6; ++f) h += FE[lane][f] * ws[OFF_LQ1W + j*6 + f];
                h = lk(h);
                lo += h * ws[OFF_LQ2W + j];
            }
            val = lo * ws[OFF_QW + lane];
        }
        #pragma unroll
        for (int d = 32; d >= 1; d >>= 1) val += __shfl_xor(val, d);
        if (lane == 0) {
            float emit = val * (1.f / 30.f);
            float z = ws[OFF_SOB];
            z += ga0 * ws[OFF_SOW + 0];
            z += ga1 * ws[OFF_SOW + 1];
            z += ga2 * ws[OFF_SOW + 2];
            z += emit * ws[OFF_SOW + 3];
            float sc = 1.f / (1.f + expf(-z));
            if (bf) ((__hip_bfloat16*)out)[1 + n] = __float2bfloat16(sc);
            else    ((float*)out)[1 + n] = sc;
        }
    }
}

// ---------------- kernel 3: doc-level head ----------------
__global__ __launch_bounds__(256) void k_final(const void* docgaf_in, void* out, const float* ws) {
    const int tid = threadIdx.x;
    const int bf = ((const int*)ws)[0];
    __shared__ float red[256];
    float m = -1e30f;
    for (int i = tid; i < 4000; i += 256) {
        float v = bf ? __bfloat162float(((const __hip_bfloat16*)out)[1 + i])
                     : ((const float*)out)[1 + i];
        m = fmaxf(m, v);
    }
    red[tid] = m;
    __syncthreads();
    for (int off = 128; off > 0; off >>= 1) {
        if (tid < off) red[tid] = fmaxf(red[tid], red[tid + off]);
        __syncthreads();
    }
    if (tid == 0) {
        float f = ws[OFF_FLB] + red[0] * ws[OFF_FLW + 0];
        for (int i = 0; i < 4; ++i) f += ldx(docgaf_in, i, bf) * ws[OFF_FLW + 1 + i];
        if (bf) ((__hip_bfloat16*)out)[0] = __float2bfloat16(f);
        else    ((float*)out)[0] = f;
    }
}

extern "C" void kernel_launch(void* const* d_in, const int* in_sizes, int n_in,
                              void* d_out, int out_size, void* d_ws, size_t ws_size,
                              hipStream_t stream) {
    float* ws = (float*)d_ws;
    k_prep<<<3, 256, 0, stream>>>(d_in[0], d_in[2], d_in[3], d_in[5], d_in[6], d_in[7], d_in[8],
                                  d_in[9], d_in[10], d_in[11], d_in[12], d_in[13], d_in[14],
                                  d_in[15], d_in[16], d_in[17], d_in[18], ws);
    k_main<<<4000, 128, 0, stream>>>(d_in[0], d_in[1], d_out, ws);
    k_final<<<1, 256, 0, stream>>>(d_in[4], d_out, ws);
}